// Round 2
// baseline (82.653 us; speedup 1.0000x reference)
//
#include <hip/hip_runtime.h>

// loss = BCE_with_logits(pred, psi) + 10 * mean_valid((d_i - d_j)^2)
// d = pred - logit(clamp(psi, eps, 1-eps)), valid = |psi_i - psi_j| >= 0.05.
// N = 8192, output: 1 fp32 scalar.
//
// R1: register-block 4 rows/thread (amortize LDS column read over 4 pairs;
// was LDS-pipe-bound at 1 ds_read_b64/pair) + wave-uniform scalar count via
// popcount(ballot) (5 VALU ops/pair, count on scalar pipe).

constexpr float DPSI_T    = 0.05f;
constexpr float LOGIT_EPS = 1e-7f;
constexpr int   CB  = 128;   // columns per block (LDS tile)
constexpr int   RPT = 4;     // rows per thread
constexpr int   TPB = 256;   // threads per block -> 1024 rows per block

__device__ __forceinline__ float logit_f(float p) {
    p = fminf(fmaxf(p, LOGIT_EPS), 1.0f - LOGIT_EPS);
    return logf(p) - log1pf(-p);
}

__global__ __launch_bounds__(256) void pair_kernel(const float* __restrict__ pred,
                                                   const float* __restrict__ psi,
                                                   float* __restrict__ part_sum,
                                                   unsigned int* __restrict__ part_cnt,
                                                   int n) {
    __shared__ float2 tile[CB];
    const int tid = threadIdx.x;
    const float NANF = __int_as_float(0x7fc00000);

    // Stage column tile (psi_j, d_j). NaN psi for OOB -> compare always false.
    if (tid < CB) {
        int j = blockIdx.y * CB + tid;
        if (j < n) {
            float pj = psi[j];
            tile[tid] = make_float2(pj, pred[j] - logit_f(pj));
        } else {
            tile[tid] = make_float2(NANF, 0.0f);
        }
    }

    // 4 rows per thread, stride TPB (coalesced global loads).
    float psi_i[RPT], d_i[RPT];
    const int rbase = blockIdx.x * (TPB * RPT);
    #pragma unroll
    for (int r = 0; r < RPT; ++r) {
        int i = rbase + r * TPB + tid;
        if (i < n) {
            float pi = psi[i];
            psi_i[r] = pi;
            d_i[r]   = pred[i] - logit_f(pi);
        } else {
            psi_i[r] = NANF;
            d_i[r]   = 0.0f;
        }
    }
    __syncthreads();

    float sum[RPT] = {0.0f, 0.0f, 0.0f, 0.0f};
    unsigned int cntw = 0;   // wave-uniform (ballot/popcount), lives in SGPR
    #pragma unroll 8
    for (int k = 0; k < CB; ++k) {
        float2 t = tile[k];   // broadcast read: all lanes same address
        #pragma unroll
        for (int r = 0; r < RPT; ++r) {
            float dpsi = psi_i[r] - t.x;
            bool  v    = fabsf(dpsi) >= DPSI_T;       // NaN -> false
            float dd   = d_i[r] - t.y;
            float ddm  = v ? dd : 0.0f;               // mask before square (NaN-safe)
            sum[r] = fmaf(ddm, ddm, sum[r]);
            cntw += (unsigned int)__popcll(__ballot(v));  // scalar-pipe count
        }
    }
    // max cntw per wave: 64 lanes * 4 rows * 128 cols = 32768, fits easily.

    float s = (sum[0] + sum[1]) + (sum[2] + sum[3]);
    for (int off = 32; off; off >>= 1) s += __shfl_down(s, off);

    __shared__ float wsum[4];
    __shared__ unsigned int wcnt[4];
    int wave = tid >> 6, lane = tid & 63;
    if (lane == 0) { wsum[wave] = s; wcnt[wave] = cntw; }
    __syncthreads();
    if (tid == 0) {
        float st = (wsum[0] + wsum[1]) + (wsum[2] + wsum[3]);
        unsigned int ct = wcnt[0] + wcnt[1] + wcnt[2] + wcnt[3];
        int slot = blockIdx.x * gridDim.y + blockIdx.y;
        part_sum[slot] = st;
        part_cnt[slot] = ct;
    }
}

// One block: BCE over n elements + reduce per-block partials + finalize.
__global__ __launch_bounds__(256) void finalize_kernel(const float* __restrict__ pred,
                                                       const float* __restrict__ psi,
                                                       const int* __restrict__ flag,
                                                       const float* __restrict__ part_sum,
                                                       const unsigned int* __restrict__ part_cnt,
                                                       int nparts,
                                                       float* __restrict__ out,
                                                       int n) {
    const int tid = threadIdx.x;

    float bce = 0.0f;
    for (int i = tid; i < n; i += 256) {
        float x = pred[i], t = psi[i];
        bce += fmaxf(x, 0.0f) - x * t + log1pf(expf(-fabsf(x)));
    }
    float s = 0.0f;
    unsigned long long c = 0;
    for (int p = tid; p < nparts; p += 256) {
        s += part_sum[p];
        c += (unsigned long long)part_cnt[p];
    }

    for (int off = 32; off; off >>= 1) {
        bce += __shfl_down(bce, off);
        s   += __shfl_down(s, off);
        c   += __shfl_down(c, off);
    }
    __shared__ float b4[4], s4[4];
    __shared__ unsigned long long c4[4];
    int wave = tid >> 6, lane = tid & 63;
    if (lane == 0) { b4[wave] = bce; s4[wave] = s; c4[wave] = c; }
    __syncthreads();
    if (tid == 0) {
        float bce_total = (b4[0] + b4[1] + b4[2] + b4[3]) / (float)n;
        float s_total   = (s4[0] + s4[1]) + (s4[2] + s4[3]);
        unsigned long long c_total = c4[0] + c4[1] + c4[2] + c4[3];
        float loss = bce_total;
        if (flag[0] == 0 && c_total > 0) {
            loss += 10.0f * (s_total / (float)c_total);
        }
        out[0] = loss;
    }
}

extern "C" void kernel_launch(void* const* d_in, const int* in_sizes, int n_in,
                              void* d_out, int out_size, void* d_ws, size_t ws_size,
                              hipStream_t stream) {
    const float* pred = (const float*)d_in[0];
    const float* psi  = (const float*)d_in[1];
    const int*   flag = (const int*)d_in[2];
    float* out = (float*)d_out;
    int n = in_sizes[0];

    int nbr = (n + TPB * RPT - 1) / (TPB * RPT);   // 8 row-blocks
    int nbc = (n + CB - 1) / CB;                   // 64 col-blocks
    int nparts = nbr * nbc;                        // 512
    float* part_sum        = (float*)d_ws;
    unsigned int* part_cnt = (unsigned int*)((char*)d_ws + (size_t)nparts * sizeof(float));

    dim3 grid(nbr, nbc);
    pair_kernel<<<grid, TPB, 0, stream>>>(pred, psi, part_sum, part_cnt, n);
    finalize_kernel<<<1, 256, 0, stream>>>(pred, psi, flag, part_sum, part_cnt, nparts, out, n);
}

// Round 3
// 70.798 us; speedup vs baseline: 1.1675x; 1.1675x over previous
//
#include <hip/hip_runtime.h>

// loss = BCE_with_logits(pred, psi) + 10 * mean_valid((d_i - d_j)^2)
// d = pred - logit(clamp(psi, eps, 1-eps)), valid = |psi_i - psi_j| >= 0.05.
// N = 8192, output: 1 fp32 scalar.
//
// R3: fuse BCE into the pair kernel (per-block 16-element slice -> partial),
// finalize shrinks to a 512-slot reduce (no pred/psi re-read). Per-block
// private slots (overwrite) keep correctness independent of d_ws poison value.

constexpr float DPSI_T    = 0.05f;
constexpr float LOGIT_EPS = 1e-7f;
constexpr int   CB  = 128;   // columns per block (LDS tile)
constexpr int   RPT = 4;     // rows per thread
constexpr int   TPB = 256;   // threads per block -> 1024 rows per block

__device__ __forceinline__ float logit_f(float p) {
    p = fminf(fmaxf(p, LOGIT_EPS), 1.0f - LOGIT_EPS);
    return logf(p) - log1pf(-p);
}

__global__ __launch_bounds__(256) void pair_kernel(const float* __restrict__ pred,
                                                   const float* __restrict__ psi,
                                                   float* __restrict__ part_sum,
                                                   unsigned int* __restrict__ part_cnt,
                                                   float* __restrict__ part_bce,
                                                   int n) {
    __shared__ float2 tile[CB];
    const int tid = threadIdx.x;
    const float NANF = __int_as_float(0x7fc00000);
    const int slot = blockIdx.x * gridDim.y + blockIdx.y;

    // Stage column tile (psi_j, d_j). NaN psi for OOB -> compare always false.
    if (tid < CB) {
        int j = blockIdx.y * CB + tid;
        if (j < n) {
            float pj = psi[j];
            tile[tid] = make_float2(pj, pred[j] - logit_f(pj));
        } else {
            tile[tid] = make_float2(NANF, 0.0f);
        }
    }

    // BCE slice: this block covers elements [slot*16, slot*16+16).
    float bce = 0.0f;
    if (tid < 16) {
        int i = slot * 16 + tid;
        if (i < n) {
            float x = pred[i], t = psi[i];
            bce = fmaxf(x, 0.0f) - x * t + log1pf(expf(-fabsf(x)));
        }
    }

    // 4 rows per thread, stride TPB (coalesced global loads).
    float psi_i[RPT], d_i[RPT];
    const int rbase = blockIdx.x * (TPB * RPT);
    #pragma unroll
    for (int r = 0; r < RPT; ++r) {
        int i = rbase + r * TPB + tid;
        if (i < n) {
            float pi = psi[i];
            psi_i[r] = pi;
            d_i[r]   = pred[i] - logit_f(pi);
        } else {
            psi_i[r] = NANF;
            d_i[r]   = 0.0f;
        }
    }
    __syncthreads();

    float sum[RPT] = {0.0f, 0.0f, 0.0f, 0.0f};
    unsigned int cntw = 0;   // wave-uniform count via ballot/popcount (SGPR)
    #pragma unroll 8
    for (int k = 0; k < CB; ++k) {
        float2 t = tile[k];   // broadcast read: all lanes same address
        #pragma unroll
        for (int r = 0; r < RPT; ++r) {
            float dpsi = psi_i[r] - t.x;
            bool  v    = fabsf(dpsi) >= DPSI_T;       // NaN -> false
            float dd   = d_i[r] - t.y;
            float ddm  = v ? dd : 0.0f;               // mask before square (NaN-safe)
            sum[r] = fmaf(ddm, ddm, sum[r]);
            cntw += (unsigned int)__popcll(__ballot(v));  // shares the v_cmp
        }
    }

    float s = (sum[0] + sum[1]) + (sum[2] + sum[3]);
    for (int off = 32; off; off >>= 1) {
        s   += __shfl_down(s, off);
        bce += __shfl_down(bce, off);   // lanes >=16 contribute 0
    }

    __shared__ float wsum[4];
    __shared__ unsigned int wcnt[4];
    int wave = tid >> 6, lane = tid & 63;
    if (lane == 0) { wsum[wave] = s; wcnt[wave] = cntw; }
    __syncthreads();
    if (tid == 0) {
        float st = (wsum[0] + wsum[1]) + (wsum[2] + wsum[3]);
        unsigned int ct = wcnt[0] + wcnt[1] + wcnt[2] + wcnt[3];
        part_sum[slot] = st;
        part_cnt[slot] = ct;
        part_bce[slot] = bce;   // wave-0 reduced value (only wave 0 had nonzero)
    }
}

// One block: reduce 512 per-block partials + finalize.
__global__ __launch_bounds__(256) void finalize_kernel(const int* __restrict__ flag,
                                                       const float* __restrict__ part_sum,
                                                       const unsigned int* __restrict__ part_cnt,
                                                       const float* __restrict__ part_bce,
                                                       int nparts,
                                                       float* __restrict__ out,
                                                       int n) {
    const int tid = threadIdx.x;

    float s = 0.0f, b = 0.0f;
    unsigned long long c = 0;
    for (int p = tid; p < nparts; p += 256) {
        s += part_sum[p];
        b += part_bce[p];
        c += (unsigned long long)part_cnt[p];
    }

    for (int off = 32; off; off >>= 1) {
        s += __shfl_down(s, off);
        b += __shfl_down(b, off);
        c += __shfl_down(c, off);
    }
    __shared__ float s4[4], b4[4];
    __shared__ unsigned long long c4[4];
    int wave = tid >> 6, lane = tid & 63;
    if (lane == 0) { s4[wave] = s; b4[wave] = b; c4[wave] = c; }
    __syncthreads();
    if (tid == 0) {
        float s_total = (s4[0] + s4[1]) + (s4[2] + s4[3]);
        float b_total = (b4[0] + b4[1]) + (b4[2] + b4[3]);
        unsigned long long c_total = c4[0] + c4[1] + c4[2] + c4[3];
        float loss = b_total / (float)n;
        if (flag[0] == 0 && c_total > 0) {
            loss += 10.0f * (s_total / (float)c_total);
        }
        out[0] = loss;
    }
}

extern "C" void kernel_launch(void* const* d_in, const int* in_sizes, int n_in,
                              void* d_out, int out_size, void* d_ws, size_t ws_size,
                              hipStream_t stream) {
    const float* pred = (const float*)d_in[0];
    const float* psi  = (const float*)d_in[1];
    const int*   flag = (const int*)d_in[2];
    float* out = (float*)d_out;
    int n = in_sizes[0];

    int nbr = (n + TPB * RPT - 1) / (TPB * RPT);   // 8 row-blocks
    int nbc = (n + CB - 1) / CB;                   // 64 col-blocks
    int nparts = nbr * nbc;                        // 512
    float* part_sum        = (float*)d_ws;
    unsigned int* part_cnt = (unsigned int*)((char*)d_ws + (size_t)nparts * sizeof(float));
    float* part_bce        = (float*)((char*)d_ws + (size_t)2 * nparts * sizeof(float));

    dim3 grid(nbr, nbc);
    pair_kernel<<<grid, TPB, 0, stream>>>(pred, psi, part_sum, part_cnt, part_bce, n);
    finalize_kernel<<<1, 256, 0, stream>>>(flag, part_sum, part_cnt, part_bce, nparts, out, n);
}